// Round 4
// baseline (265.300 us; speedup 1.0000x reference)
//
#include <hip/hip_runtime.h>

// TropConv2D: out[b,ho,wo,f] = max_k(patch_k + w[k,f]) - min_k(patch_k + w[k,f])
// x: (8,32,32,32) f32 NHWC, w: (288,64) f32, out: (8,30,30,64) f32
// k = (i*3 + j)*32 + c   (TF extract_patches ordering)
//
// v4: anti-spill + LDS-traffic fix.
//   v3 spilled wreg[72] (VGPR_Count=64; WRITE_SIZE 70.6 MB == 960*256*72*4B
//   exactly) -> kernel was spill-bound. Fixes:
//   - amdgpu_waves_per_eu(4,4): pin 4 waves/EU -> 128-VGPR budget, no spill.
//   - weight preload split per window row i: wreg[24] live (3 batched L2
//     windows/wave, hidden at 16 waves/CU).
//   - rolling 3-column register window over the LDS patch tile: 60
//     ds_read_b128 broadcasts/wave (was 144).
//   - max3/min3 helpers -> v_max3_f32/v_min3_f32 trees.
//   grid = 8*30*4 = 960 blocks, 256 thr = 4 waves; lane=filter, wave=chan slice.
//   Max/min associative -> channel-split partials exact (absmax 0).

#define C_IN 32
#define NF 64
#define H_OUT 30
#define W_OUT 30
#define W_IN 32

static __device__ __forceinline__ float max3f(float a, float b, float c) {
    return fmaxf(fmaxf(a, b), c);
}
static __device__ __forceinline__ float min3f(float a, float b, float c) {
    return fminf(fminf(a, b), c);
}

__global__ __launch_bounds__(256)
__attribute__((amdgpu_waves_per_eu(4, 4)))
void tropconv_kernel(
    const float* __restrict__ x,
    const float* __restrict__ w,
    float* __restrict__ out) {
    const int bx = blockIdx.x;            // 0..959
    const int q = bx & 3;                 // row quarter
    const int bho = bx >> 2;              // b*30 + ho
    const int b = bho / H_OUT;
    const int ho = bho - b * H_OUT;
    const int tid = threadIdx.x;
    const int lane = tid & 63;            // filter index
    const int wave = tid >> 6;            // channel-slice 0..3

    const int col0 = q * 8;
    const int npx = (q == 3) ? 6 : 8;     // block-uniform
    const int ncols = (q == 3) ? 8 : 10;

    __shared__ __align__(16) float xs[3 * 10 * C_IN];  // 3.75 KB patch tile
    __shared__ float pmx[4][8][NF];                    // 8 KB partial max
    __shared__ float pmn[4][8][NF];                    // 8 KB partial min

    // ---- Stage patch rows (contiguous NHWC segments) ----
    {
        const int nf4_row = ncols * (C_IN / 4);    // 80 or 64 float4 per row
        const int total_f4 = 3 * nf4_row;          // 240 or 192
        if (tid < total_f4) {
            const int r = tid / nf4_row;
            const int cc = tid - r * nf4_row;
            const float4* __restrict__ src = (const float4*)(
                x + ((size_t)((b * 32 + ho + r) * W_IN + col0)) * C_IN);
            ((float4*)xs)[r * 80 + cc] = src[cc];
        }
    }
    __syncthreads();

    float mx[8], mn[8];
    #pragma unroll
    for (int t = 0; t < 8; ++t) { mx[t] = -INFINITY; mn[t] = INFINITY; }

    #pragma unroll
    for (int i = 0; i < 3; ++i) {
        // ---- Batched preload: 24 weights for window row i (one window) ----
        // w[((i*3+j)*32 + wave*8 + cc)*64 + lane]
        float wreg[24];
        {
            const float* __restrict__ wp =
                w + ((size_t)((i * 3) * C_IN + wave * 8)) * NF + lane;
            #pragma unroll
            for (int j = 0; j < 3; ++j)
                #pragma unroll
                for (int cc = 0; cc < 8; ++cc)
                    wreg[j * 8 + cc] = wp[(j * C_IN + cc) * NF];
        }

        const float* __restrict__ xrow = xs + i * (10 * C_IN) + wave * 8;

        // Rolling 3-column register window (8 floats per column)
        float4 c0a = ((const float4*)(xrow + 0 * C_IN))[0];
        float4 c0b = ((const float4*)(xrow + 0 * C_IN))[1];
        float4 c1a = ((const float4*)(xrow + 1 * C_IN))[0];
        float4 c1b = ((const float4*)(xrow + 1 * C_IN))[1];

        #pragma unroll
        for (int px = 0; px < 8; ++px) {
            if (px < npx) {               // block-uniform predicate
                float4 c2a = ((const float4*)(xrow + (px + 2) * C_IN))[0];
                float4 c2b = ((const float4*)(xrow + (px + 2) * C_IN))[1];

                // j=0 -> c0, j=1 -> c1, j=2 -> c2
                float s0  = c0a.x + wreg[0],  s1  = c0a.y + wreg[1];
                float s2  = c0a.z + wreg[2],  s3  = c0a.w + wreg[3];
                float s4  = c0b.x + wreg[4],  s5  = c0b.y + wreg[5];
                float s6  = c0b.z + wreg[6],  s7  = c0b.w + wreg[7];
                float s8  = c1a.x + wreg[8],  s9  = c1a.y + wreg[9];
                float s10 = c1a.z + wreg[10], s11 = c1a.w + wreg[11];
                float s12 = c1b.x + wreg[12], s13 = c1b.y + wreg[13];
                float s14 = c1b.z + wreg[14], s15 = c1b.w + wreg[15];
                float s16 = c2a.x + wreg[16], s17 = c2a.y + wreg[17];
                float s18 = c2a.z + wreg[18], s19 = c2a.w + wreg[19];
                float s20 = c2b.x + wreg[20], s21 = c2b.y + wreg[21];
                float s22 = c2b.z + wreg[22], s23 = c2b.w + wreg[23];

                mx[px] = max3f(
                    max3f(max3f(s0, s1, s2), max3f(s3, s4, s5), max3f(s6, s7, s8)),
                    max3f(max3f(s9, s10, s11), max3f(s12, s13, s14), max3f(s15, s16, s17)),
                    max3f(max3f(s18, s19, s20), max3f(s21, s22, s23), mx[px]));
                mn[px] = min3f(
                    min3f(min3f(s0, s1, s2), min3f(s3, s4, s5), min3f(s6, s7, s8)),
                    min3f(min3f(s9, s10, s11), min3f(s12, s13, s14), min3f(s15, s16, s17)),
                    min3f(min3f(s18, s19, s20), min3f(s21, s22, s23), mn[px]));

                // roll the window
                c0a = c1a; c0b = c1b; c1a = c2a; c1b = c2b;
            }
        }
    }

    #pragma unroll
    for (int px = 0; px < 8; ++px) {
        if (px < npx) {
            pmx[wave][px][lane] = mx[px];
            pmn[wave][px][lane] = mn[px];
        }
    }
    __syncthreads();

    // ---- Cross-wave combine (exact: max/min associative) ----
    const int nout = npx * NF;            // 512 or 384
    for (int e = tid; e < nout; e += 256) {
        const int px = e >> 6;
        const int f = e & 63;
        float a = fmaxf(fmaxf(pmx[0][px][f], pmx[1][px][f]),
                        fmaxf(pmx[2][px][f], pmx[3][px][f]));
        float m = fminf(fminf(pmn[0][px][f], pmn[1][px][f]),
                        fminf(pmn[2][px][f], pmn[3][px][f]));
        out[((size_t)bho * W_OUT + (col0 + px)) * NF + f] = a - m;
    }
}

extern "C" void kernel_launch(void* const* d_in, const int* in_sizes, int n_in,
                              void* d_out, int out_size, void* d_ws, size_t ws_size,
                              hipStream_t stream) {
    const float* x = (const float*)d_in[0];   // 8*32*32*32
    const float* w = (const float*)d_in[1];   // 288*64
    float* out = (float*)d_out;               // 8*30*30*64

    dim3 grid(8 * H_OUT * 4);                 // 960 blocks
    dim3 block(256);
    tropconv_kernel<<<grid, block, 0, stream>>>(x, w, out);
}

// Round 5
// 63.292 us; speedup vs baseline: 4.1917x; 4.1917x over previous
//
#include <hip/hip_runtime.h>

// TropConv2D: out[b,ho,wo,f] = max_k(patch_k + w[k,f]) - min_k(patch_k + w[k,f])
// x: (8,32,32,32) f32 NHWC, w: (288,64) f32 (72 KB), out: (8,30,30,64) f32
// k = (i*3 + j)*32 + c   (TF extract_patches ordering)
//
// v5: occupancy + latency fix, designed for <=64 VGPRs (v3/v4 spilled when the
//   allocator held to its 64-VGPR / 8-waves-per-EU heuristic; WRITE_SIZE was
//   70->435 MB of scratch. Lesson: don't fight the allocator).
//   - 512 thr = 8 waves/block; wave = 4-channel slice (c = wave*4..+3).
//     960 blocks -> 30 waves/CU (~7.5/SIMD, near HW max TLP).
//   - Weight prefetch: ij+1's 4 weights load while ij computes -> L2 latency
//     hidden. Live floats/thread ~45 -> no spill at 64 VGPRs.
//   - Inner body per (ij,px): 1 broadcast ds_read_b128 (imm offsets) +
//     4 add + 2 v_max3 + 2 v_min3. No predicates (q=3 extra px discarded).
//   - Max/min associative -> 8-way channel-split partials exact (absmax 0).

#define C_IN 32
#define NF 64
#define H_OUT 30
#define W_OUT 30
#define W_IN 32

static __device__ __forceinline__ float max3f(float a, float b, float c) {
    return fmaxf(fmaxf(a, b), c);
}
static __device__ __forceinline__ float min3f(float a, float b, float c) {
    return fminf(fminf(a, b), c);
}

__global__ __launch_bounds__(512) void tropconv_kernel(
    const float* __restrict__ x,
    const float* __restrict__ w,
    float* __restrict__ out) {
    const int bx = blockIdx.x;            // 0..959
    const int q = bx & 3;                 // row quarter
    const int bho = bx >> 2;              // b*30 + ho
    const int b = bho / H_OUT;
    const int ho = bho - b * H_OUT;
    const int tid = threadIdx.x;
    const int lane = tid & 63;            // filter index
    const int wave = tid >> 6;            // channel-slice 0..7 (c = wave*4..+3)

    const int col0 = q * 8;
    const int npx = (q == 3) ? 6 : 8;
    const int ncols = (q == 3) ? 8 : 10;  // staged input cols (OOB-safe for q=3)

    __shared__ __align__(16) float xs[3 * 10 * C_IN];  // 3.75 KB patch tile
    __shared__ float pmx[8][8][NF];                    // 16 KB partial max
    __shared__ float pmn[8][8][NF];                    // 16 KB partial min

    // ---- Stage patch rows (contiguous NHWC segments, coalesced float4) ----
    {
        const int nf4_row = ncols * (C_IN / 4);    // 80 or 64 float4 per row
        const int total_f4 = 3 * nf4_row;          // 240 or 192 (< 512)
        if (tid < total_f4) {
            const int r = tid / nf4_row;
            const int cc = tid - r * nf4_row;
            const float4* __restrict__ src = (const float4*)(
                x + ((size_t)((b * 32 + ho + r) * W_IN + col0)) * C_IN);
            ((float4*)xs)[r * 80 + cc] = src[cc];
        }
    }

    // Weight base for this wave's channel slice: w[(ij*32 + wave*4 + cc)*64 + lane]
    const float* __restrict__ wbase = w + (size_t)(wave * 4) * NF + lane;

    float wc[4];                           // current ij weights (prefetched)
    #pragma unroll
    for (int cc = 0; cc < 4; ++cc) wc[cc] = wbase[cc * NF];

    __syncthreads();

    float mx[8], mn[8];
    #pragma unroll
    for (int t = 0; t < 8; ++t) { mx[t] = -INFINITY; mn[t] = INFINITY; }

    #pragma unroll
    for (int ij = 0; ij < 9; ++ij) {
        // prefetch next ij's weights (hidden behind this ij's compute)
        float wn[4];
        if (ij < 8) {
            #pragma unroll
            for (int cc = 0; cc < 4; ++cc)
                wn[cc] = wbase[((ij + 1) * C_IN + cc) * NF];
        }

        const int i = ij / 3;
        const int j = ij - i * 3;
        // single vaddr per ij; px becomes an immediate offset (px*128 B)
        const float* __restrict__ xrow = xs + (i * 10 + j) * C_IN + wave * 4;

        #pragma unroll
        for (int px = 0; px < 8; ++px) {   // q=3: px>=6 reads uninit LDS, discarded
            float4 p = *(const float4*)(xrow + px * C_IN);  // broadcast b128
            float s0 = p.x + wc[0];
            float s1 = p.y + wc[1];
            float s2 = p.z + wc[2];
            float s3 = p.w + wc[3];
            mx[px] = max3f(max3f(s0, s1, s2), s3, mx[px]);
            mn[px] = min3f(min3f(s0, s1, s2), s3, mn[px]);
        }

        #pragma unroll
        for (int cc = 0; cc < 4; ++cc) wc[cc] = wn[cc];
    }

    #pragma unroll
    for (int px = 0; px < 8; ++px) {
        pmx[wave][px][lane] = mx[px];
        pmn[wave][px][lane] = mn[px];
    }
    __syncthreads();

    // ---- Cross-wave combine (exact: max/min associative) ----
    const int nout = npx * NF;            // 512 or 384
    if (tid < nout) {
        const int px = tid >> 6;
        const int f = tid & 63;
        float a = fmaxf(fmaxf(fmaxf(pmx[0][px][f], pmx[1][px][f]),
                              fmaxf(pmx[2][px][f], pmx[3][px][f])),
                        fmaxf(fmaxf(pmx[4][px][f], pmx[5][px][f]),
                              fmaxf(pmx[6][px][f], pmx[7][px][f])));
        float m = fminf(fminf(fminf(pmn[0][px][f], pmn[1][px][f]),
                              fminf(pmn[2][px][f], pmn[3][px][f])),
                        fminf(fminf(pmn[4][px][f], pmn[5][px][f]),
                              fminf(pmn[6][px][f], pmn[7][px][f])));
        out[((size_t)bho * W_OUT + (col0 + px)) * NF + f] = a - m;
    }
}

extern "C" void kernel_launch(void* const* d_in, const int* in_sizes, int n_in,
                              void* d_out, int out_size, void* d_ws, size_t ws_size,
                              hipStream_t stream) {
    const float* x = (const float*)d_in[0];   // 8*32*32*32
    const float* w = (const float*)d_in[1];   // 288*64
    float* out = (float*)d_out;               // 8*30*30*64

    dim3 grid(8 * H_OUT * 4);                 // 960 blocks
    dim3 block(512);
    tropconv_kernel<<<grid, block, 0, stream>>>(x, w, out);
}